// Round 8
// baseline (324.321 us; speedup 1.0000x reference)
//
#include <hip/hip_runtime.h>
#include <hip/hip_bf16.h>

#define B_    4
#define C_    128
#define HW_   16384
#define K_    1024
#define NEG_  (-10000000.0f)
#define SCALE_ 0.08838834764831845f   // 128^-0.5

using bf16 = __hip_bfloat16;
typedef __bf16 b8v __attribute__((ext_vector_type(8)));
typedef __bf16 b4v __attribute__((ext_vector_type(4)));
typedef __bf16 b2v __attribute__((ext_vector_type(2)));
typedef float  f4v __attribute__((ext_vector_type(4)));

__device__ __forceinline__ b8v ldb8(const void* p) { return *(const b8v*)p; }
__device__ __forceinline__ b4v ldb4(const void* p) { return *(const b4v*)p; }
__device__ __forceinline__ void storev(float* p, float v) { *p = v; }
__device__ __forceinline__ void storev(bf16* p, float v)  { *p = __float2bfloat16(v); }

#define XSTRIDE 272   // 256 B row + 16 pad: b128 frag reads land on the bank floor

// ---------------------------------------------------------------------------
// conv-bn-relu helpers for the kv (VALU) path
// ---------------------------------------------------------------------------
__device__ __forceinline__ void layer128_lds(const float* __restrict__ Xs, float* __restrict__ Ysh,
                                             const float* __restrict__ W,
                                             const float* __restrict__ sc, const float* __restrict__ sh)
{
    const int t = threadIdx.x;
    const int o = t & 127;
    const int half = t >> 7;
    float acc[16];
#pragma unroll
    for (int p = 0; p < 16; ++p) acc[p] = 0.f;
    const float* wrow  = W + o * 128;
    const float* xbase = Xs + half * 16;
    for (int c = 0; c < 128; c += 4) {
        const float4 w4 = *(const float4*)(wrow + c);
        const float wj[4] = {w4.x, w4.y, w4.z, w4.w};
#pragma unroll
        for (int j = 0; j < 4; ++j) {
            const float* xr = xbase + (c + j) * 33;
#pragma unroll
            for (int p = 0; p < 16; ++p) acc[p] += wj[j] * xr[p];
        }
    }
    const float s = sc[o], h = sh[o];
    float* yb = Ysh + o * 33 + half * 16;
#pragma unroll
    for (int p = 0; p < 16; ++p) yb[p] = fmaxf(fmaf(s, acc[p], h), 0.f);
}

template <typename OutT>
__device__ __forceinline__ void layer128_store(const float* __restrict__ Xs, OutT* __restrict__ outp,
                                               const float* __restrict__ W,
                                               const float* __restrict__ sc, const float* __restrict__ sh)
{
    const int t = threadIdx.x;
    const int o = t & 127;
    const int half = t >> 7;
    float acc[16];
#pragma unroll
    for (int p = 0; p < 16; ++p) acc[p] = 0.f;
    const float* wrow  = W + o * 128;
    const float* xbase = Xs + half * 16;
    for (int c = 0; c < 128; c += 4) {
        const float4 w4 = *(const float4*)(wrow + c);
        const float wj[4] = {w4.x, w4.y, w4.z, w4.w};
#pragma unroll
        for (int j = 0; j < 4; ++j) {
            const float* xr = xbase + (c + j) * 33;
#pragma unroll
            for (int p = 0; p < 16; ++p) acc[p] += wj[j] * xr[p];
        }
    }
    const float s = sc[o], h = sh[o];
#pragma unroll
    for (int p = 0; p < 16; ++p) {
        float v = fmaxf(fmaf(s, acc[p], h), 0.f);
        storev(&outp[(size_t)(half * 16 + p) * 128 + o], v);
    }
}

// ---------------------------------------------------------------------------
// prep_kernel: one launch doing three independent jobs, partitioned by block:
//   [0,1024)     tq:    transpose query [b][c][p] f32 -> qt [b][p][c] bf16
//   [1024,1152)  kv:    k (2 layers) -> kbuf [b][k][c]; v (1 layer) -> vbuf [b][c][k]
//   [1152,1600)  wprep: fold BN scale into weights, f32 -> bf16
// 256 threads; shared 33.8 KB LDS union -> 4 blocks/CU.
// ---------------------------------------------------------------------------
__global__ __launch_bounds__(256) void prep_kernel(
    const float* __restrict__ query, const float* __restrict__ key, const float* __restrict__ val,
    const float* __restrict__ Wk1, const float* __restrict__ sk1, const float* __restrict__ bk1,
    const float* __restrict__ Wk2, const float* __restrict__ sk2, const float* __restrict__ bk2,
    const float* __restrict__ Wv,  const float* __restrict__ sv,  const float* __restrict__ bv,
    const float* __restrict__ Wq1, const float* __restrict__ sq1,
    const float* __restrict__ Wq2, const float* __restrict__ sq2,
    const float* __restrict__ Wo,  const float* __restrict__ so,
    const float* __restrict__ Wb,  const float* __restrict__ sb,
    bf16* __restrict__ qt, bf16* __restrict__ kbuf, bf16* __restrict__ vbuf,
    __bf16* __restrict__ Wq1p, __bf16* __restrict__ Wq2p,
    __bf16* __restrict__ Wop,  __bf16* __restrict__ Wbp)
{
    __shared__ __align__(16) float S[2 * 128 * 33];   // 33.8 KB union
    const int blk = blockIdx.x;
    const int t   = threadIdx.x;

    if (blk < 1024) {
        // ---- tq: 64-position tile
        float* Xs = S;                        // used as [64][129]
        const int p0 = (blk & 255) * 64, b = blk >> 8;
        const int pl = t & 63, cg = t >> 6;
#pragma unroll 4
        for (int i = 0; i < 32; ++i) {
            const int c = cg * 32 + i;
            Xs[pl * 129 + c] = query[(size_t)(b * 128 + c) * HW_ + p0 + pl];
        }
        __syncthreads();
#pragma unroll 4
        for (int it = 0; it < 16; ++it) {
            const int p = it * 4 + cg;
            b2v pk;
            pk[0] = (__bf16)Xs[p * 129 + 2 * pl];
            pk[1] = (__bf16)Xs[p * 129 + 2 * pl + 1];
            *(b2v*)(qt + ((size_t)b * HW_ + p0 + p) * 128 + 2 * pl) = pk;
        }
    } else if (blk < 1152) {
        // ---- kv: 32-key tile
        float* X = S;
        float* Y = S + 128 * 33;
        const int local = blk - 1024;
        const int p0 = (local & 31) * 32, b = local >> 5;

        for (int e = t; e < 4096; e += 256) {
            int c = e >> 5, p = e & 31;
            X[c * 33 + p] = key[(size_t)(b * 128 + c) * K_ + p0 + p];
        }
        __syncthreads();
        layer128_lds(X, Y, Wk1, sk1, bk1);
        __syncthreads();
        layer128_store(Y, kbuf + (size_t)(b * K_ + p0) * 128, Wk2, sk2, bk2);
        __syncthreads();
        for (int e = t; e < 4096; e += 256) {
            int c = e >> 5, p = e & 31;
            X[c * 33 + p] = val[(size_t)(b * 128 + c) * K_ + p0 + p];
        }
        __syncthreads();
        layer128_lds(X, Y, Wv, sv, bv);
        __syncthreads();
        for (int e = t; e < 4096; e += 256) {
            int c = e >> 5, p = e & 31;
            vbuf[(size_t)(b * 128 + c) * K_ + p0 + p] = __float2bfloat16(Y[c * 33 + p]);
        }
    } else {
        // ---- wprep
        const int idx = (blk - 1152) * 256 + t;
        if (idx < 16384)      { Wq1p[idx] = (__bf16)(Wq1[idx] * sq1[idx >> 7]); }
        else if (idx < 32768) { const int i = idx - 16384; Wq2p[i] = (__bf16)(Wq2[i] * sq2[i >> 7]); }
        else if (idx < 49152) { const int i = idx - 32768; Wop[i]  = (__bf16)(Wo[i]  * so[i >> 7]); }
        else                  { const int i = idx - 49152; Wbp[i]  = (__bf16)(Wb[i]  * sb[i >> 8]); }
    }
}

// ---------------------------------------------------------------------------
// q projection via MFMA, LDS-staged activations (unchanged from R7).
// grid (HW/128, B), 256 threads.
// ---------------------------------------------------------------------------
__global__ __launch_bounds__(256, 2) void qproj_kernel(
    const bf16* __restrict__ qt,
    const __bf16* __restrict__ W1, const float* __restrict__ sh1,
    const __bf16* __restrict__ W2, const float* __restrict__ sh2,
    bf16* __restrict__ qbuf)
{
    __shared__ __align__(16) char Xs[128 * XSTRIDE];
    __shared__ __align__(16) __bf16 Ys[128 * 136];
    const int t = threadIdx.x, w = t >> 6, lane = t & 63;
    const int pl = lane & 15, quad = lane >> 4;
    const int n0 = blockIdx.x * 128, b = blockIdx.y;
    const int ob = 32 * w;

    {
        const char* qg = (const char*)(qt + ((size_t)b * HW_ + n0) * 128) + t * 16;
        char* xl = Xs + (t >> 4) * XSTRIDE + (t & 15) * 16;
#pragma unroll
        for (int i = 0; i < 8; ++i)
            *(float4*)(xl + i * 16 * XSTRIDE) = *(const float4*)(qg + i * 4096);
    }

    b8v W1f[2][4], W2f[2][4];
#pragma unroll
    for (int mt = 0; mt < 2; ++mt)
#pragma unroll
        for (int s = 0; s < 4; ++s) {
            W1f[mt][s] = ldb8(W1 + (ob + mt * 16 + pl) * 128 + s * 32 + quad * 8);
            W2f[mt][s] = ldb8(W2 + (ob + mt * 16 + pl) * 128 + s * 32 + quad * 8);
        }
    __syncthreads();

    f4v acc[2][8];
#pragma unroll
    for (int mt = 0; mt < 2; ++mt)
#pragma unroll
        for (int nt = 0; nt < 8; ++nt) acc[mt][nt] = (f4v){0.f, 0.f, 0.f, 0.f};

#pragma unroll
    for (int s = 0; s < 4; ++s) {
        b8v Bf[8];
#pragma unroll
        for (int nt = 0; nt < 8; ++nt)
            Bf[nt] = ldb8(Xs + (nt * 16 + pl) * XSTRIDE + s * 64 + quad * 16);
#pragma unroll
        for (int mt = 0; mt < 2; ++mt)
#pragma unroll
            for (int nt = 0; nt < 8; ++nt)
                acc[mt][nt] = __builtin_amdgcn_mfma_f32_16x16x32_bf16(W1f[mt][s], Bf[nt], acc[mt][nt], 0, 0, 0);
    }

#pragma unroll
    for (int mt = 0; mt < 2; ++mt) {
        const float4 s4 = *(const float4*)(sh1 + ob + mt * 16 + quad * 4);
        const float shf[4] = {s4.x, s4.y, s4.z, s4.w};
#pragma unroll
        for (int nt = 0; nt < 8; ++nt) {
            b4v y;
#pragma unroll
            for (int r = 0; r < 4; ++r) y[r] = (__bf16)fmaxf(acc[mt][nt][r] + shf[r], 0.f);
            *(b4v*)&Ys[(nt * 16 + pl) * 136 + ob + mt * 16 + quad * 4] = y;
        }
    }
    __syncthreads();

    f4v acc2[2][8];
#pragma unroll
    for (int mt = 0; mt < 2; ++mt)
#pragma unroll
        for (int nt = 0; nt < 8; ++nt) acc2[mt][nt] = (f4v){0.f, 0.f, 0.f, 0.f};

#pragma unroll
    for (int s = 0; s < 4; ++s) {
        b8v Bf[8];
#pragma unroll
        for (int nt = 0; nt < 8; ++nt)
            Bf[nt] = *(const b8v*)&Ys[(nt * 16 + pl) * 136 + s * 32 + quad * 8];
#pragma unroll
        for (int mt = 0; mt < 2; ++mt)
#pragma unroll
            for (int nt = 0; nt < 8; ++nt)
                acc2[mt][nt] = __builtin_amdgcn_mfma_f32_16x16x32_bf16(W2f[mt][s], Bf[nt], acc2[mt][nt], 0, 0, 0);
    }

    bf16* qb = qbuf + ((size_t)b * HW_ + n0) * 128;
#pragma unroll
    for (int mt = 0; mt < 2; ++mt) {
        const float4 s4 = *(const float4*)(sh2 + ob + mt * 16 + quad * 4);
        const float shf[4] = {s4.x, s4.y, s4.z, s4.w};
#pragma unroll
        for (int nt = 0; nt < 8; ++nt) {
            b4v y;
#pragma unroll
            for (int r = 0; r < 4; ++r) y[r] = (__bf16)fmaxf(acc2[mt][nt][r] + shf[r], 0.f);
            *(b4v*)(qb + (size_t)(nt * 16 + pl) * 128 + ob + mt * 16 + quad * 4) = y;
        }
    }
}

// ---------------------------------------------------------------------------
// flash attention (unchanged from R6). grid (HW/64, B), 256 threads.
// ---------------------------------------------------------------------------
#define KSTRIDE 272
#define VSTRIDE 136
__global__ __launch_bounds__(256, 2) void attn_kernel(
    const bf16* __restrict__ qbuf, const bf16* __restrict__ kbuf, const bf16* __restrict__ vbuf,
    const int* __restrict__ mask, bf16* __restrict__ ctxbuf)
{
    __shared__ __align__(16) float bias[K_];
    __shared__ __align__(16) char ktile[64 * KSTRIDE];
    __shared__ __align__(16) char vtile[128 * VSTRIDE];

    const int t    = threadIdx.x;
    const int w    = t >> 6;
    const int lane = t & 63;
    const int m    = lane & 15;
    const int quad = lane >> 4;
    const int q0   = blockIdx.x * 64;
    const int b    = blockIdx.y;

    for (int i = t; i < K_; i += 256)
        bias[i] = (mask[b * K_ + i] != 0) ? 0.f : NEG_;

    b8v qf[4];
    {
        const bf16* qrow = qbuf + ((size_t)b * HW_ + q0 + w * 16 + m) * 128;
#pragma unroll
        for (int s = 0; s < 4; ++s) qf[s] = ldb8(qrow + s * 32 + quad * 8);
    }

    const bf16* kpt = kbuf + (size_t)b * K_ * 128;
    const bf16* vpt = vbuf + (size_t)b * 128 * K_;

    const char* kg = (const char*)kpt + t * 16;
    const char* vg = (const char*)(vpt + (size_t)(t >> 3) * K_) + (t & 7) * 16;
    char* kl = ktile + (t >> 4) * KSTRIDE + (t & 15) * 16;
    char* vl = vtile + (t >> 3) * VSTRIDE + (t & 7) * 16;

    float4 k_r0 = *(const float4*)(kg);
    float4 k_r1 = *(const float4*)(kg + 4096);
    float4 k_r2 = *(const float4*)(kg + 8192);
    float4 k_r3 = *(const float4*)(kg + 12288);
    float4 v_r0 = *(const float4*)(vg);
    float4 v_r1 = *(const float4*)(vg + 65536);
    float4 v_r2 = *(const float4*)(vg + 131072);
    float4 v_r3 = *(const float4*)(vg + 196608);

    f4v acc[8];
#pragma unroll
    for (int i = 0; i < 8; ++i) acc[i] = (f4v){0.f, 0.f, 0.f, 0.f};
    float mrun = -3.0e38f, lrun = 0.f;

    for (int chunk = 0; chunk < 16; ++chunk) {
        const int k0 = chunk * 64;

        *(float4*)(kl)                = k_r0;
        *(float4*)(kl + 16 * KSTRIDE) = k_r1;
        *(float4*)(kl + 32 * KSTRIDE) = k_r2;
        *(float4*)(kl + 48 * KSTRIDE) = k_r3;
        *(float4*)(vl)                = v_r0;
        *(float4*)(vl + 32 * VSTRIDE) = v_r1;
        *(float4*)(vl + 64 * VSTRIDE) = v_r2;
        *(float4*)(vl + 96 * VSTRIDE) = v_r3;
        __syncthreads();

        if (chunk < 15) {
            const char* kgn = kg + (chunk + 1) * 16384;
            const char* vgn = vg + (chunk + 1) * 128;
            k_r0 = *(const float4*)(kgn);
            k_r1 = *(const float4*)(kgn + 4096);
            k_r2 = *(const float4*)(kgn + 8192);
            k_r3 = *(const float4*)(kgn + 12288);
            v_r0 = *(const float4*)(vgn);
            v_r1 = *(const float4*)(vgn + 65536);
            v_r2 = *(const float4*)(vgn + 131072);
            v_r3 = *(const float4*)(vgn + 196608);
        }

        f4v sv[4];
#pragma unroll
        for (int kt = 0; kt < 4; ++kt) {
            f4v a = (f4v){0.f, 0.f, 0.f, 0.f};
            const char* krow = ktile + (kt * 16 + m) * KSTRIDE + quad * 16;
#pragma unroll
            for (int s = 0; s < 4; ++s)
                a = __builtin_amdgcn_mfma_f32_16x16x32_bf16(ldb8(krow + s * 64), qf[s], a, 0, 0, 0);
            const float4 b4 = *(const float4*)&bias[k0 + kt * 16 + quad * 4];
            const float bb4[4] = {b4.x, b4.y, b4.z, b4.w};
#pragma unroll
            for (int r = 0; r < 4; ++r) sv[kt][r] = a[r] * SCALE_ + bb4[r];
        }

        float mloc = sv[0][0];
#pragma unroll
        for (int kt = 0; kt < 4; ++kt)
#pragma unroll
            for (int r = 0; r < 4; ++r) mloc = fmaxf(mloc, sv[kt][r]);
        mloc = fmaxf(mloc, __shfl_xor(mloc, 16, 64));
        mloc = fmaxf(mloc, __shfl_xor(mloc, 32, 64));
        const float mn = fmaxf(mrun, mloc);
        const float alpha = __expf(mrun - mn);
        mrun = mn;

        b4v pk[4];
        float rs = 0.f;
#pragma unroll
        for (int kt = 0; kt < 4; ++kt)
#pragma unroll
            for (int r = 0; r < 4; ++r) {
                const float p = __expf(sv[kt][r] - mn);
                rs += p;
                pk[kt][r] = (__bf16)p;
            }
        rs += __shfl_xor(rs, 16, 64);
        rs += __shfl_xor(rs, 32, 64);
        lrun = lrun * alpha + rs;

        float alr[4];
#pragma unroll
        for (int r = 0; r < 4; ++r) alr[r] = __shfl(alpha, quad * 4 + r, 64);
#pragma unroll
        for (int ct = 0; ct < 8; ++ct)
#pragma unroll
            for (int r = 0; r < 4; ++r) acc[ct][r] *= alr[r];

        const b8v A0 = __builtin_shufflevector(pk[0], pk[1], 0, 1, 2, 3, 4, 5, 6, 7);
        const b8v A1 = __builtin_shufflevector(pk[2], pk[3], 0, 1, 2, 3, 4, 5, 6, 7);
#pragma unroll
        for (int ct = 0; ct < 8; ++ct) {
            const char* vrow = vtile + (ct * 16 + m) * VSTRIDE + quad * 8;
            const b8v B0 = __builtin_shufflevector(ldb4(vrow),      ldb4(vrow + 32), 0, 1, 2, 3, 4, 5, 6, 7);
            const b8v B1 = __builtin_shufflevector(ldb4(vrow + 64), ldb4(vrow + 96), 0, 1, 2, 3, 4, 5, 6, 7);
            acc[ct] = __builtin_amdgcn_mfma_f32_16x16x32_bf16(A0, B0, acc[ct], 0, 0, 0);
            acc[ct] = __builtin_amdgcn_mfma_f32_16x16x32_bf16(A1, B1, acc[ct], 0, 0, 0);
        }
        __syncthreads();
    }

    float inv[4];
#pragma unroll
    for (int r = 0; r < 4; ++r) inv[r] = 1.f / __shfl(lrun, quad * 4 + r, 64);
    bf16* crow = ctxbuf + ((size_t)b * HW_ + q0 + w * 16) * 128;
#pragma unroll
    for (int ct = 0; ct < 8; ++ct)
#pragma unroll
        for (int r = 0; r < 4; ++r)
            crow[(size_t)(quad * 4 + r) * 128 + ct * 16 + m] = __float2bfloat16(acc[ct][r] * inv[r]);
}

// ---------------------------------------------------------------------------
// Final: ctx2 = relu(Wo'@ctx + bo); out = relu(Wb'@[ctx2;qt] + bb).
// Layer 2 runs in two M-halves (rows 0-127, 128-255): per-half weight frags
// (16 b8v/wave) hoisted OUT of the ks loop; acc2 is 64 VGPR per half.
// grid (HW/128, B), 256 threads.
// ---------------------------------------------------------------------------
__global__ __launch_bounds__(256, 2) void final_kernel(
    const bf16* __restrict__ ctx, const bf16* __restrict__ qt,
    const __bf16* __restrict__ Wop, const float* __restrict__ bo,
    const __bf16* __restrict__ Wbp, const float* __restrict__ bb,
    float* __restrict__ out)
{
    __shared__ __align__(16) char Xs[128 * XSTRIDE];
    __shared__ __align__(16) __bf16 Ys[128 * 136];
    const int t = threadIdx.x, w = t >> 6, lane = t & 63;
    const int pl = lane & 15, quad = lane >> 4;
    const int n0 = blockIdx.x * 128, b = blockIdx.y;
    const int ob = 32 * w;

    char* xl = Xs + (t >> 4) * XSTRIDE + (t & 15) * 16;

    // ---- stage ctx tile (contiguous 32 KB) into Xs
    {
        const char* cg = (const char*)(ctx + ((size_t)b * HW_ + n0) * 128) + t * 16;
#pragma unroll
        for (int i = 0; i < 8; ++i)
            *(float4*)(xl + i * 16 * XSTRIDE) = *(const float4*)(cg + i * 4096);
    }

    b8v Wof[2][4];
#pragma unroll
    for (int mt = 0; mt < 2; ++mt)
#pragma unroll
        for (int s = 0; s < 4; ++s)
            Wof[mt][s] = ldb8(Wop + (ob + mt * 16 + pl) * 128 + s * 32 + quad * 8);
    __syncthreads();

    // ---- issue qt staging loads now; consumed after layer 1
    const char* qg = (const char*)(qt + ((size_t)b * HW_ + n0) * 128) + t * 16;
    float4 q_s0 = *(const float4*)(qg);
    float4 q_s1 = *(const float4*)(qg + 4096);
    float4 q_s2 = *(const float4*)(qg + 8192);
    float4 q_s3 = *(const float4*)(qg + 12288);
    float4 q_s4 = *(const float4*)(qg + 16384);
    float4 q_s5 = *(const float4*)(qg + 20480);
    float4 q_s6 = *(const float4*)(qg + 24576);
    float4 q_s7 = *(const float4*)(qg + 28672);

    // ---- layer 1: ctx2 = relu(Wo' @ ctx + bo)
    f4v acc1[2][8];
#pragma unroll
    for (int mt = 0; mt < 2; ++mt)
#pragma unroll
        for (int nt = 0; nt < 8; ++nt) acc1[mt][nt] = (f4v){0.f, 0.f, 0.f, 0.f};

#pragma unroll
    for (int s = 0; s < 4; ++s) {
        b8v Bf[8];
#pragma unroll
        for (int nt = 0; nt < 8; ++nt)
            Bf[nt] = ldb8(Xs + (nt * 16 + pl) * XSTRIDE + s * 64 + quad * 16);
#pragma unroll
        for (int mt = 0; mt < 2; ++mt)
#pragma unroll
            for (int nt = 0; nt < 8; ++nt)
                acc1[mt][nt] = __builtin_amdgcn_mfma_f32_16x16x32_bf16(Wof[mt][s], Bf[nt], acc1[mt][nt], 0, 0, 0);
    }

#pragma unroll
    for (int mt = 0; mt < 2; ++mt) {
        const float4 s4 = *(const float4*)(bo + ob + mt * 16 + quad * 4);
        const float shf[4] = {s4.x, s4.y, s4.z, s4.w};
#pragma unroll
        for (int nt = 0; nt < 8; ++nt) {
            b4v y;
#pragma unroll
            for (int r = 0; r < 4; ++r) y[r] = (__bf16)fmaxf(acc1[mt][nt][r] + shf[r], 0.f);
            *(b4v*)&Ys[(nt * 16 + pl) * 136 + ob + mt * 16 + quad * 4] = y;
        }
    }
    __syncthreads();    // Xs reads done, Ys visible

    // ---- restage Xs with qt tile
    *(float4*)(xl)                 = q_s0;
    *(float4*)(xl + 16 * XSTRIDE)  = q_s1;
    *(float4*)(xl + 32 * XSTRIDE)  = q_s2;
    *(float4*)(xl + 48 * XSTRIDE)  = q_s3;
    *(float4*)(xl + 64 * XSTRIDE)  = q_s4;
    *(float4*)(xl + 80 * XSTRIDE)  = q_s5;
    *(float4*)(xl + 96 * XSTRIDE)  = q_s6;
    *(float4*)(xl + 112 * XSTRIDE) = q_s7;
    __syncthreads();

    // ---- layer 2 in two M-halves: wave w -> rows 128h + 32w .. +31
#pragma unroll 1
    for (int h = 0; h < 2; ++h) {
        const int mb = 128 * h + 32 * w;

        b8v Wf[2][8];
#pragma unroll
        for (int mt = 0; mt < 2; ++mt)
#pragma unroll
            for (int ks = 0; ks < 8; ++ks)
                Wf[mt][ks] = ldb8(Wbp + (size_t)(mb + mt * 16 + pl) * 256 + ks * 32 + quad * 8);

        f4v acc2[2][8];
#pragma unroll
        for (int mt = 0; mt < 2; ++mt)
#pragma unroll
            for (int nt = 0; nt < 8; ++nt) acc2[mt][nt] = (f4v){0.f, 0.f, 0.f, 0.f};

#pragma unroll
        for (int ks = 0; ks < 8; ++ks) {
            b8v Bf[8];
            if (ks < 4) {
#pragma unroll
                for (int nt = 0; nt < 8; ++nt)
                    Bf[nt] = *(const b8v*)&Ys[(nt * 16 + pl) * 136 + ks * 32 + quad * 8];
            } else {
#pragma unroll
                for (int nt = 0; nt < 8; ++nt)
                    Bf[nt] = ldb8(Xs + (nt * 16 + pl) * XSTRIDE + (ks - 4) * 64 + quad * 16);
            }
#pragma unroll
            for (int mt = 0; mt < 2; ++mt)
#pragma unroll
                for (int nt = 0; nt < 8; ++nt)
                    acc2[mt][nt] = __builtin_amdgcn_mfma_f32_16x16x32_bf16(Wf[mt][ks], Bf[nt], acc2[mt][nt], 0, 0, 0);
        }

#pragma unroll
        for (int mt = 0; mt < 2; ++mt) {
            const float4 s4 = *(const float4*)(bb + mb + mt * 16 + quad * 4);
            const float shf[4] = {s4.x, s4.y, s4.z, s4.w};
#pragma unroll
            for (int nt = 0; nt < 8; ++nt)
#pragma unroll
                for (int r = 0; r < 4; ++r)
                    out[(size_t)(b * 256 + mb + mt * 16 + quad * 4 + r) * HW_ + n0 + nt * 16 + pl]
                        = fmaxf(acc2[mt][nt][r] + shf[r], 0.f);
        }
    }
}

// ---------------------------------------------------------------------------
extern "C" void kernel_launch(void* const* d_in, const int* in_sizes, int n_in,
                              void* d_out, int out_size, void* d_ws, size_t ws_size,
                              hipStream_t stream)
{
    const float* query = (const float*)d_in[0];
    const float* key   = (const float*)d_in[1];
    const float* val   = (const float*)d_in[2];
    const int*   mask  = (const int*)  d_in[3];
    const float* Wq1 = (const float*)d_in[4];  const float* sq1 = (const float*)d_in[5];  const float* bq1 = (const float*)d_in[6];
    const float* Wq2 = (const float*)d_in[7];  const float* sq2 = (const float*)d_in[8];  const float* bq2 = (const float*)d_in[9];
    const float* Wk1 = (const float*)d_in[10]; const float* sk1 = (const float*)d_in[11]; const float* bk1 = (const float*)d_in[12];
    const float* Wk2 = (const float*)d_in[13]; const float* sk2 = (const float*)d_in[14]; const float* bk2 = (const float*)d_in[15];
    const float* Wv  = (const float*)d_in[16]; const float* sv  = (const float*)d_in[17]; const float* bv  = (const float*)d_in[18];
    const float* Wo  = (const float*)d_in[19]; const float* so  = (const float*)d_in[20]; const float* bo  = (const float*)d_in[21];
    const float* Wb  = (const float*)d_in[22]; const float* sb  = (const float*)d_in[23]; const float* bb  = (const float*)d_in[24];

    char* ws = (char*)d_ws;
    bf16*   kbuf = (bf16*)(ws);                        // [B][K][C] bf16  : 1 MB
    bf16*   vbuf = (bf16*)(ws + (1u << 20));           // [B][C][K] bf16  : 1 MB
    bf16*   qbuf = (bf16*)(ws + (2u << 20));           // [B][HW][C] bf16 : 16 MB
    bf16*   ctxb = (bf16*)(ws + (18u << 20));          // [B][HW][C] bf16 : 16 MB
    bf16*   qt   = (bf16*)(ws + (34u << 20));          // [B][HW][C] bf16 : 16 MB
    __bf16* Wq1p = (__bf16*)(ws + (50u << 20));                  // 32 KB
    __bf16* Wq2p = (__bf16*)(ws + (50u << 20) + (32u << 10));    // 32 KB
    __bf16* Wop  = (__bf16*)(ws + (50u << 20) + (64u << 10));    // 32 KB
    __bf16* Wbp  = (__bf16*)(ws + (50u << 20) + (96u << 10));    // 128 KB
    float* outp = (float*)d_out;

    prep_kernel<<<1600, 256, 0, stream>>>(
        query, key, val,
        Wk1, sk1, bk1, Wk2, sk2, bk2, Wv, sv, bv,
        Wq1, sq1, Wq2, sq2, Wo, so, Wb, sb,
        qt, kbuf, vbuf, Wq1p, Wq2p, Wop, Wbp);
    qproj_kernel<<<dim3(HW_ / 128, B_), 256, 0, stream>>>(
        qt, Wq1p, bq1, Wq2p, bq2, qbuf);
    attn_kernel<<<dim3(HW_ / 64, B_), 256, 0, stream>>>(
        qbuf, kbuf, vbuf, mask, ctxb);
    final_kernel<<<dim3(HW_ / 128, B_), 256, 0, stream>>>(
        ctxb, qt, Wop, bo, Wbp, bb, outp);
}

// Round 9
// 247.121 us; speedup vs baseline: 1.3124x; 1.3124x over previous
//
#include <hip/hip_runtime.h>
#include <hip/hip_bf16.h>

#define B_    4
#define C_    128
#define HW_   16384
#define K_    1024
#define NEG_  (-10000000.0f)
#define SCALE_ 0.08838834764831845f   // 128^-0.5

using bf16 = __hip_bfloat16;
typedef __bf16 b8v __attribute__((ext_vector_type(8)));
typedef __bf16 b4v __attribute__((ext_vector_type(4)));
typedef __bf16 b2v __attribute__((ext_vector_type(2)));
typedef float  f4v __attribute__((ext_vector_type(4)));

__device__ __forceinline__ b8v ldb8(const void* p) { return *(const b8v*)p; }
__device__ __forceinline__ b4v ldb4(const void* p) { return *(const b4v*)p; }

#define XSTRIDE 272   // 256 B row + 16 pad: b128 frag reads land on the bank floor

// ---------------------------------------------------------------------------
// wprep: fold BN scale into rows, f32 -> bf16. 7 matrices, 163840 elems,
// grid 640 x 256 exact.
// ---------------------------------------------------------------------------
__global__ __launch_bounds__(256) void wprep_kernel(
    const float* __restrict__ Wq1, const float* __restrict__ sq1,
    const float* __restrict__ Wq2, const float* __restrict__ sq2,
    const float* __restrict__ Wo,  const float* __restrict__ so,
    const float* __restrict__ Wb,  const float* __restrict__ sb,
    const float* __restrict__ Wk1, const float* __restrict__ sk1,
    const float* __restrict__ Wk2, const float* __restrict__ sk2,
    const float* __restrict__ Wv,  const float* __restrict__ sv,
    __bf16* __restrict__ Wq1p, __bf16* __restrict__ Wq2p,
    __bf16* __restrict__ Wop,  __bf16* __restrict__ Wbp,
    __bf16* __restrict__ Wk1p, __bf16* __restrict__ Wk2p, __bf16* __restrict__ Wvp)
{
    const int idx = blockIdx.x * 256 + threadIdx.x;
    if (idx < 16384)       { Wq1p[idx] = (__bf16)(Wq1[idx] * sq1[idx >> 7]); }
    else if (idx < 32768)  { const int i = idx - 16384;  Wq2p[i] = (__bf16)(Wq2[i] * sq2[i >> 7]); }
    else if (idx < 49152)  { const int i = idx - 32768;  Wop[i]  = (__bf16)(Wo[i]  * so[i >> 7]); }
    else if (idx < 114688) { const int i = idx - 49152;  Wbp[i]  = (__bf16)(Wb[i]  * sb[i >> 8]); }
    else if (idx < 131072) { const int i = idx - 114688; Wk1p[i] = (__bf16)(Wk1[i] * sk1[i >> 7]); }
    else if (idx < 147456) { const int i = idx - 131072; Wk2p[i] = (__bf16)(Wk2[i] * sk2[i >> 7]); }
    else                   { const int i = idx - 147456; Wvp[i]  = (__bf16)(Wv[i]  * sv[i >> 7]); }
}

// ---------------------------------------------------------------------------
// txp: transpose [b][c][L] f32 -> [b][p][c] bf16 for query (L=HW), key, val
// (L=K). grid (256+16+16, B), 256 threads.
// ---------------------------------------------------------------------------
__global__ __launch_bounds__(256) void txp_kernel(
    const float* __restrict__ query, const float* __restrict__ key, const float* __restrict__ val,
    bf16* __restrict__ qt, bf16* __restrict__ kT, bf16* __restrict__ vT)
{
    __shared__ float Xs[64 * 129];
    const int seg = blockIdx.x, b = blockIdx.y, t = threadIdx.x;
    const float* src; bf16* dst; int L, p0;
    if (seg < 256)      { src = query; dst = qt; L = HW_; p0 = seg * 64; }
    else if (seg < 272) { src = key;   dst = kT; L = K_;  p0 = (seg - 256) * 64; }
    else                { src = val;   dst = vT; L = K_;  p0 = (seg - 272) * 64; }

    const int pl = t & 63, cg = t >> 6;
#pragma unroll 4
    for (int i = 0; i < 32; ++i) {
        const int c = cg * 32 + i;
        Xs[pl * 129 + c] = src[(size_t)(b * 128 + c) * L + p0 + pl];
    }
    __syncthreads();
#pragma unroll 4
    for (int it = 0; it < 16; ++it) {
        const int p = it * 4 + cg;
        b2v pk;
        pk[0] = (__bf16)Xs[p * 129 + 2 * pl];
        pk[1] = (__bf16)Xs[p * 129 + 2 * pl + 1];
        *(b2v*)(dst + ((size_t)b * L + p0 + p) * 128 + 2 * pl) = pk;
    }
}

// ---------------------------------------------------------------------------
// Generic MFMA 2-layer conv-bn-relu body on a 128-position tile.
// src/dst already offset to the tile base ([pos][128] bf16).
// ---------------------------------------------------------------------------
__device__ __forceinline__ void proj2_body(
    const bf16* __restrict__ src,
    const __bf16* __restrict__ W1, const float* __restrict__ sh1,
    const __bf16* __restrict__ W2, const float* __restrict__ sh2,
    bf16* __restrict__ dst, char* Xs, __bf16* Ys)
{
    const int t = threadIdx.x, w = t >> 6, lane = t & 63;
    const int pl = lane & 15, quad = lane >> 4;
    const int ob = 32 * w;

    {
        const char* sg = (const char*)src + t * 16;
        char* xl = Xs + (t >> 4) * XSTRIDE + (t & 15) * 16;
#pragma unroll
        for (int i = 0; i < 8; ++i)
            *(float4*)(xl + i * 16 * XSTRIDE) = *(const float4*)(sg + i * 4096);
    }

    b8v W1f[2][4], W2f[2][4];
#pragma unroll
    for (int mt = 0; mt < 2; ++mt)
#pragma unroll
        for (int s = 0; s < 4; ++s) {
            W1f[mt][s] = ldb8(W1 + (ob + mt * 16 + pl) * 128 + s * 32 + quad * 8);
            W2f[mt][s] = ldb8(W2 + (ob + mt * 16 + pl) * 128 + s * 32 + quad * 8);
        }
    __syncthreads();

    f4v acc[2][8];
#pragma unroll
    for (int mt = 0; mt < 2; ++mt)
#pragma unroll
        for (int nt = 0; nt < 8; ++nt) acc[mt][nt] = (f4v){0.f, 0.f, 0.f, 0.f};

#pragma unroll
    for (int s = 0; s < 4; ++s) {
        b8v Bf[8];
#pragma unroll
        for (int nt = 0; nt < 8; ++nt)
            Bf[nt] = ldb8(Xs + (nt * 16 + pl) * XSTRIDE + s * 64 + quad * 16);
#pragma unroll
        for (int mt = 0; mt < 2; ++mt)
#pragma unroll
            for (int nt = 0; nt < 8; ++nt)
                acc[mt][nt] = __builtin_amdgcn_mfma_f32_16x16x32_bf16(W1f[mt][s], Bf[nt], acc[mt][nt], 0, 0, 0);
    }

#pragma unroll
    for (int mt = 0; mt < 2; ++mt) {
        const float4 s4 = *(const float4*)(sh1 + ob + mt * 16 + quad * 4);
        const float shf[4] = {s4.x, s4.y, s4.z, s4.w};
#pragma unroll
        for (int nt = 0; nt < 8; ++nt) {
            b4v y;
#pragma unroll
            for (int r = 0; r < 4; ++r) y[r] = (__bf16)fmaxf(acc[mt][nt][r] + shf[r], 0.f);
            *(b4v*)&Ys[(nt * 16 + pl) * 136 + ob + mt * 16 + quad * 4] = y;
        }
    }
    __syncthreads();

    f4v acc2[2][8];
#pragma unroll
    for (int mt = 0; mt < 2; ++mt)
#pragma unroll
        for (int nt = 0; nt < 8; ++nt) acc2[mt][nt] = (f4v){0.f, 0.f, 0.f, 0.f};

#pragma unroll
    for (int s = 0; s < 4; ++s) {
        b8v Bf[8];
#pragma unroll
        for (int nt = 0; nt < 8; ++nt)
            Bf[nt] = *(const b8v*)&Ys[(nt * 16 + pl) * 136 + s * 32 + quad * 8];
#pragma unroll
        for (int mt = 0; mt < 2; ++mt)
#pragma unroll
            for (int nt = 0; nt < 8; ++nt)
                acc2[mt][nt] = __builtin_amdgcn_mfma_f32_16x16x32_bf16(W2f[mt][s], Bf[nt], acc2[mt][nt], 0, 0, 0);
    }

#pragma unroll
    for (int mt = 0; mt < 2; ++mt) {
        const float4 s4 = *(const float4*)(sh2 + ob + mt * 16 + quad * 4);
        const float shf[4] = {s4.x, s4.y, s4.z, s4.w};
#pragma unroll
        for (int nt = 0; nt < 8; ++nt) {
            b4v y;
#pragma unroll
            for (int r = 0; r < 4; ++r) y[r] = (__bf16)fmaxf(acc2[mt][nt][r] + shf[r], 0.f);
            *(b4v*)(dst + (size_t)(nt * 16 + pl) * 128 + ob + mt * 16 + quad * 4) = y;
        }
    }
}

// ---------------------------------------------------------------------------
// proj: grid (136, B). x<128: q projection tile. x>=128: k projection tile
// (8 tiles of 128 keys) + v single layer with transposed [c][k] output.
// ---------------------------------------------------------------------------
__global__ __launch_bounds__(256, 2) void proj_kernel(
    const bf16* __restrict__ qt, const bf16* __restrict__ kT, const bf16* __restrict__ vT,
    const __bf16* __restrict__ Wq1p, const float* __restrict__ bq1,
    const __bf16* __restrict__ Wq2p, const float* __restrict__ bq2,
    const __bf16* __restrict__ Wk1p, const float* __restrict__ bk1,
    const __bf16* __restrict__ Wk2p, const float* __restrict__ bk2,
    const __bf16* __restrict__ Wvp,  const float* __restrict__ bv,
    bf16* __restrict__ qbuf, bf16* __restrict__ kbuf, bf16* __restrict__ vbuf)
{
    __shared__ __align__(16) char Xs[128 * XSTRIDE];
    __shared__ __align__(16) __bf16 Ys[128 * 136];
    const int t = threadIdx.x, w = t >> 6, lane = t & 63;
    const int pl = lane & 15, quad = lane >> 4;
    const int b = blockIdx.y;

    if (blockIdx.x < 128) {
        const int n0 = blockIdx.x * 128;
        proj2_body(qt + ((size_t)b * HW_ + n0) * 128, Wq1p, bq1, Wq2p, bq2,
                   qbuf + ((size_t)b * HW_ + n0) * 128, Xs, Ys);
        return;
    }

    // ---- k projection (2 layers), tile of 128 keys
    const int n0 = (blockIdx.x - 128) * 128;
    proj2_body(kT + ((size_t)b * K_ + n0) * 128, Wk1p, bk1, Wk2p, bk2,
               kbuf + ((size_t)b * K_ + n0) * 128, Xs, Ys);
    __syncthreads();

    // ---- v projection (1 layer): A = Wv' (M=channel), B = vT rows (N=key),
    //      output vbuf [b][c][k]
    {
        const char* sg = (const char*)(vT + ((size_t)b * K_ + n0) * 128) + t * 16;
        char* xl = Xs + (t >> 4) * XSTRIDE + (t & 15) * 16;
#pragma unroll
        for (int i = 0; i < 8; ++i)
            *(float4*)(xl + i * 16 * XSTRIDE) = *(const float4*)(sg + i * 4096);
    }
    const int ob = 32 * w;
    b8v Wf[2][4];
#pragma unroll
    for (int mt = 0; mt < 2; ++mt)
#pragma unroll
        for (int s = 0; s < 4; ++s)
            Wf[mt][s] = ldb8(Wvp + (ob + mt * 16 + pl) * 128 + s * 32 + quad * 8);
    __syncthreads();

    f4v acc[2][8];
#pragma unroll
    for (int mt = 0; mt < 2; ++mt)
#pragma unroll
        for (int nt = 0; nt < 8; ++nt) acc[mt][nt] = (f4v){0.f, 0.f, 0.f, 0.f};

#pragma unroll
    for (int s = 0; s < 4; ++s) {
        b8v Bf[8];
#pragma unroll
        for (int nt = 0; nt < 8; ++nt)
            Bf[nt] = ldb8(Xs + (nt * 16 + pl) * XSTRIDE + s * 64 + quad * 16);
#pragma unroll
        for (int mt = 0; mt < 2; ++mt)
#pragma unroll
            for (int nt = 0; nt < 8; ++nt)
                acc[mt][nt] = __builtin_amdgcn_mfma_f32_16x16x32_bf16(Wf[mt][s], Bf[nt], acc[mt][nt], 0, 0, 0);
    }

    // epilogue: D row = channel ob+mt*16+quad*4+r, col = key n0+nt*16+pl
    bf16* vb = vbuf + (size_t)b * 128 * K_;
#pragma unroll
    for (int mt = 0; mt < 2; ++mt) {
        const float4 s4 = *(const float4*)(bv + ob + mt * 16 + quad * 4);
        const float shf[4] = {s4.x, s4.y, s4.z, s4.w};
#pragma unroll
        for (int nt = 0; nt < 8; ++nt)
#pragma unroll
            for (int r = 0; r < 4; ++r)
                vb[(size_t)(ob + mt * 16 + quad * 4 + r) * K_ + n0 + nt * 16 + pl]
                    = __float2bfloat16(fmaxf(acc[mt][nt][r] + shf[r], 0.f));
    }
}

// ---------------------------------------------------------------------------
// flash attention (unchanged from R6). grid (HW/64, B), 256 threads.
// ---------------------------------------------------------------------------
#define KSTRIDE 272
#define VSTRIDE 136
__global__ __launch_bounds__(256, 2) void attn_kernel(
    const bf16* __restrict__ qbuf, const bf16* __restrict__ kbuf, const bf16* __restrict__ vbuf,
    const int* __restrict__ mask, bf16* __restrict__ ctxbuf)
{
    __shared__ __align__(16) float bias[K_];
    __shared__ __align__(16) char ktile[64 * KSTRIDE];
    __shared__ __align__(16) char vtile[128 * VSTRIDE];

    const int t    = threadIdx.x;
    const int w    = t >> 6;
    const int lane = t & 63;
    const int m    = lane & 15;
    const int quad = lane >> 4;
    const int q0   = blockIdx.x * 64;
    const int b    = blockIdx.y;

    for (int i = t; i < K_; i += 256)
        bias[i] = (mask[b * K_ + i] != 0) ? 0.f : NEG_;

    b8v qf[4];
    {
        const bf16* qrow = qbuf + ((size_t)b * HW_ + q0 + w * 16 + m) * 128;
#pragma unroll
        for (int s = 0; s < 4; ++s) qf[s] = ldb8(qrow + s * 32 + quad * 8);
    }

    const bf16* kpt = kbuf + (size_t)b * K_ * 128;
    const bf16* vpt = vbuf + (size_t)b * 128 * K_;

    const char* kg = (const char*)kpt + t * 16;
    const char* vg = (const char*)(vpt + (size_t)(t >> 3) * K_) + (t & 7) * 16;
    char* kl = ktile + (t >> 4) * KSTRIDE + (t & 15) * 16;
    char* vl = vtile + (t >> 3) * VSTRIDE + (t & 7) * 16;

    float4 k_r0 = *(const float4*)(kg);
    float4 k_r1 = *(const float4*)(kg + 4096);
    float4 k_r2 = *(const float4*)(kg + 8192);
    float4 k_r3 = *(const float4*)(kg + 12288);
    float4 v_r0 = *(const float4*)(vg);
    float4 v_r1 = *(const float4*)(vg + 65536);
    float4 v_r2 = *(const float4*)(vg + 131072);
    float4 v_r3 = *(const float4*)(vg + 196608);

    f4v acc[8];
#pragma unroll
    for (int i = 0; i < 8; ++i) acc[i] = (f4v){0.f, 0.f, 0.f, 0.f};
    float mrun = -3.0e38f, lrun = 0.f;

    for (int chunk = 0; chunk < 16; ++chunk) {
        const int k0 = chunk * 64;

        *(float4*)(kl)                = k_r0;
        *(float4*)(kl + 16 * KSTRIDE) = k_r1;
        *(float4*)(kl + 32 * KSTRIDE) = k_r2;
        *(float4*)(kl + 48 * KSTRIDE) = k_r3;
        *(float4*)(vl)                = v_r0;
        *(float4*)(vl + 32 * VSTRIDE) = v_r1;
        *(float4*)(vl + 64 * VSTRIDE) = v_r2;
        *(float4*)(vl + 96 * VSTRIDE) = v_r3;
        __syncthreads();

        if (chunk < 15) {
            const char* kgn = kg + (chunk + 1) * 16384;
            const char* vgn = vg + (chunk + 1) * 128;
            k_r0 = *(const float4*)(kgn);
            k_r1 = *(const float4*)(kgn + 4096);
            k_r2 = *(const float4*)(kgn + 8192);
            k_r3 = *(const float4*)(kgn + 12288);
            v_r0 = *(const float4*)(vgn);
            v_r1 = *(const float4*)(vgn + 65536);
            v_r2 = *(const float4*)(vgn + 131072);
            v_r3 = *(const float4*)(vgn + 196608);
        }

        f4v sv[4];
#pragma unroll
        for (int kt = 0; kt < 4; ++kt) {
            f4v a = (f4v){0.f, 0.f, 0.f, 0.f};
            const char* krow = ktile + (kt * 16 + m) * KSTRIDE + quad * 16;
#pragma unroll
            for (int s = 0; s < 4; ++s)
                a = __builtin_amdgcn_mfma_f32_16x16x32_bf16(ldb8(krow + s * 64), qf[s], a, 0, 0, 0);
            const float4 b4 = *(const float4*)&bias[k0 + kt * 16 + quad * 4];
            const float bb4[4] = {b4.x, b4.y, b4.z, b4.w};
#pragma unroll
            for (int r = 0; r < 4; ++r) sv[kt][r] = a[r] * SCALE_ + bb4[r];
        }

        float mloc = sv[0][0];
#pragma unroll
        for (int kt = 0; kt < 4; ++kt)
#pragma unroll
            for (int r = 0; r < 4; ++r) mloc = fmaxf(mloc, sv[kt][r]);
        mloc = fmaxf(mloc, __shfl_xor(mloc, 16, 64));
        mloc = fmaxf(mloc, __shfl_xor(mloc, 32, 64));
        const float mn = fmaxf(mrun, mloc);
        const float alpha = __expf(mrun - mn);
        mrun = mn;

        b4v pk[4];
        float rs = 0.f;
#pragma unroll
        for (int kt = 0; kt < 4; ++kt)
#pragma unroll
            for (int r = 0; r < 4; ++r) {
                const float p = __expf(sv[kt][r] - mn);
                rs += p;
                pk[kt][r] = (__bf16)p;
            }
        rs += __shfl_xor(rs, 16, 64);
        rs += __shfl_xor(rs, 32, 64);
        lrun = lrun * alpha + rs;

        float alr[4];
#pragma unroll
        for (int r = 0; r < 4; ++r) alr[r] = __shfl(alpha, quad * 4 + r, 64);
#pragma unroll
        for (int ct = 0; ct < 8; ++ct)
#pragma unroll
            for (int r = 0; r < 4; ++r) acc[ct][r] *= alr[r];

        const b8v A0 = __builtin_shufflevector(pk[0], pk[1], 0, 1, 2, 3, 4, 5, 6, 7);
        const b8v A1 = __builtin_shufflevector(pk[2], pk[3], 0, 1, 2, 3, 4, 5, 6, 7);
#pragma unroll
        for (int ct = 0; ct < 8; ++ct) {
            const char* vrow = vtile + (ct * 16 + m) * VSTRIDE + quad * 8;
            const b8v B0 = __builtin_shufflevector(ldb4(vrow),      ldb4(vrow + 32), 0, 1, 2, 3, 4, 5, 6, 7);
            const b8v B1 = __builtin_shufflevector(ldb4(vrow + 64), ldb4(vrow + 96), 0, 1, 2, 3, 4, 5, 6, 7);
            acc[ct] = __builtin_amdgcn_mfma_f32_16x16x32_bf16(A0, B0, acc[ct], 0, 0, 0);
            acc[ct] = __builtin_amdgcn_mfma_f32_16x16x32_bf16(A1, B1, acc[ct], 0, 0, 0);
        }
        __syncthreads();
    }

    float inv[4];
#pragma unroll
    for (int r = 0; r < 4; ++r) inv[r] = 1.f / __shfl(lrun, quad * 4 + r, 64);
    bf16* crow = ctxbuf + ((size_t)b * HW_ + q0 + w * 16) * 128;
#pragma unroll
    for (int ct = 0; ct < 8; ++ct)
#pragma unroll
        for (int r = 0; r < 4; ++r)
            crow[(size_t)(quad * 4 + r) * 128 + ct * 16 + m] = __float2bfloat16(acc[ct][r] * inv[r]);
}

// ---------------------------------------------------------------------------
// Final (R7 form): ctx2 = relu(Wo'@ctx+bo); out = relu(Wb'@[ctx2;qt]+bb).
// grid (HW/128, B), 256 threads.
// ---------------------------------------------------------------------------
__global__ __launch_bounds__(256, 2) void final_kernel(
    const bf16* __restrict__ ctx, const bf16* __restrict__ qt,
    const __bf16* __restrict__ Wop, const float* __restrict__ bo,
    const __bf16* __restrict__ Wbp, const float* __restrict__ bb,
    float* __restrict__ out)
{
    __shared__ __align__(16) char Xs[128 * XSTRIDE];
    __shared__ __align__(16) __bf16 Ys[128 * 136];
    const int t = threadIdx.x, w = t >> 6, lane = t & 63;
    const int pl = lane & 15, quad = lane >> 4;
    const int n0 = blockIdx.x * 128, b = blockIdx.y;
    const int ob = 32 * w;

    char* xl = Xs + (t >> 4) * XSTRIDE + (t & 15) * 16;

    {
        const char* cg = (const char*)(ctx + ((size_t)b * HW_ + n0) * 128) + t * 16;
#pragma unroll
        for (int i = 0; i < 8; ++i)
            *(float4*)(xl + i * 16 * XSTRIDE) = *(const float4*)(cg + i * 4096);
    }

    b8v Wof[2][4];
#pragma unroll
    for (int mt = 0; mt < 2; ++mt)
#pragma unroll
        for (int s = 0; s < 4; ++s)
            Wof[mt][s] = ldb8(Wop + (ob + mt * 16 + pl) * 128 + s * 32 + quad * 8);
    __syncthreads();

    const char* qg = (const char*)(qt + ((size_t)b * HW_ + n0) * 128) + t * 16;
    float4 q_s0 = *(const float4*)(qg);
    float4 q_s1 = *(const float4*)(qg + 4096);
    float4 q_s2 = *(const float4*)(qg + 8192);
    float4 q_s3 = *(const float4*)(qg + 12288);
    float4 q_s4 = *(const float4*)(qg + 16384);
    float4 q_s5 = *(const float4*)(qg + 20480);
    float4 q_s6 = *(const float4*)(qg + 24576);
    float4 q_s7 = *(const float4*)(qg + 28672);

    f4v acc1[2][8];
#pragma unroll
    for (int mt = 0; mt < 2; ++mt)
#pragma unroll
        for (int nt = 0; nt < 8; ++nt) acc1[mt][nt] = (f4v){0.f, 0.f, 0.f, 0.f};

#pragma unroll
    for (int s = 0; s < 4; ++s) {
        b8v Bf[8];
#pragma unroll
        for (int nt = 0; nt < 8; ++nt)
            Bf[nt] = ldb8(Xs + (nt * 16 + pl) * XSTRIDE + s * 64 + quad * 16);
#pragma unroll
        for (int mt = 0; mt < 2; ++mt)
#pragma unroll
            for (int nt = 0; nt < 8; ++nt)
                acc1[mt][nt] = __builtin_amdgcn_mfma_f32_16x16x32_bf16(Wof[mt][s], Bf[nt], acc1[mt][nt], 0, 0, 0);
    }

#pragma unroll
    for (int mt = 0; mt < 2; ++mt) {
        const float4 s4 = *(const float4*)(bo + ob + mt * 16 + quad * 4);
        const float shf[4] = {s4.x, s4.y, s4.z, s4.w};
#pragma unroll
        for (int nt = 0; nt < 8; ++nt) {
            b4v y;
#pragma unroll
            for (int r = 0; r < 4; ++r) y[r] = (__bf16)fmaxf(acc1[mt][nt][r] + shf[r], 0.f);
            *(b4v*)&Ys[(nt * 16 + pl) * 136 + ob + mt * 16 + quad * 4] = y;
        }
    }
    __syncthreads();

    *(float4*)(xl)                 = q_s0;
    *(float4*)(xl + 16 * XSTRIDE)  = q_s1;
    *(float4*)(xl + 32 * XSTRIDE)  = q_s2;
    *(float4*)(xl + 48 * XSTRIDE)  = q_s3;
    *(float4*)(xl + 64 * XSTRIDE)  = q_s4;
    *(float4*)(xl + 80 * XSTRIDE)  = q_s5;
    *(float4*)(xl + 96 * XSTRIDE)  = q_s6;
    *(float4*)(xl + 112 * XSTRIDE) = q_s7;
    __syncthreads();

    f4v acc2[4][8];
#pragma unroll
    for (int mt = 0; mt < 4; ++mt)
#pragma unroll
        for (int nt = 0; nt < 8; ++nt) acc2[mt][nt] = (f4v){0.f, 0.f, 0.f, 0.f};

#pragma unroll
    for (int ks = 0; ks < 8; ++ks) {
        b8v Af[4];
#pragma unroll
        for (int mt = 0; mt < 4; ++mt)
            Af[mt] = ldb8(Wbp + (size_t)(64 * w + mt * 16 + pl) * 256 + ks * 32 + quad * 8);
        b8v Bf[8];
        if (ks < 4) {
#pragma unroll
            for (int nt = 0; nt < 8; ++nt)
                Bf[nt] = *(const b8v*)&Ys[(nt * 16 + pl) * 136 + ks * 32 + quad * 8];
        } else {
#pragma unroll
            for (int nt = 0; nt < 8; ++nt)
                Bf[nt] = ldb8(Xs + (nt * 16 + pl) * XSTRIDE + (ks - 4) * 64 + quad * 16);
        }
#pragma unroll
        for (int mt = 0; mt < 4; ++mt)
#pragma unroll
            for (int nt = 0; nt < 8; ++nt)
                acc2[mt][nt] = __builtin_amdgcn_mfma_f32_16x16x32_bf16(Af[mt], Bf[nt], acc2[mt][nt], 0, 0, 0);
    }

#pragma unroll
    for (int mt = 0; mt < 4; ++mt) {
        const float4 s4 = *(const float4*)(bb + 64 * w + mt * 16 + quad * 4);
        const float shf[4] = {s4.x, s4.y, s4.z, s4.w};
#pragma unroll
        for (int nt = 0; nt < 8; ++nt)
#pragma unroll
            for (int r = 0; r < 4; ++r)
                out[(size_t)(b * 256 + 64 * w + mt * 16 + quad * 4 + r) * HW_ + n0 + nt * 16 + pl]
                    = fmaxf(acc2[mt][nt][r] + shf[r], 0.f);
    }
}

// ---------------------------------------------------------------------------
extern "C" void kernel_launch(void* const* d_in, const int* in_sizes, int n_in,
                              void* d_out, int out_size, void* d_ws, size_t ws_size,
                              hipStream_t stream)
{
    const float* query = (const float*)d_in[0];
    const float* key   = (const float*)d_in[1];
    const float* val   = (const float*)d_in[2];
    const int*   mask  = (const int*)  d_in[3];
    const float* Wq1 = (const float*)d_in[4];  const float* sq1 = (const float*)d_in[5];  const float* bq1 = (const float*)d_in[6];
    const float* Wq2 = (const float*)d_in[7];  const float* sq2 = (const float*)d_in[8];  const float* bq2 = (const float*)d_in[9];
    const float* Wk1 = (const float*)d_in[10]; const float* sk1 = (const float*)d_in[11]; const float* bk1 = (const float*)d_in[12];
    const float* Wk2 = (const float*)d_in[13]; const float* sk2 = (const float*)d_in[14]; const float* bk2 = (const float*)d_in[15];
    const float* Wv  = (const float*)d_in[16]; const float* sv  = (const float*)d_in[17]; const float* bv  = (const float*)d_in[18];
    const float* Wo  = (const float*)d_in[19]; const float* so  = (const float*)d_in[20]; const float* bo  = (const float*)d_in[21];
    const float* Wb  = (const float*)d_in[22]; const float* sb  = (const float*)d_in[23]; const float* bb  = (const float*)d_in[24];

    char* ws = (char*)d_ws;
    bf16*   kbuf = (bf16*)(ws);                        // [B][K][C] bf16  : 1 MB
    bf16*   vbuf = (bf16*)(ws + (1u << 20));           // [B][C][K] bf16  : 1 MB
    bf16*   qbuf = (bf16*)(ws + (2u << 20));           // [B][HW][C] bf16 : 16 MB
    bf16*   ctxb = (bf16*)(ws + (18u << 20));          // [B][HW][C] bf16 : 16 MB
    bf16*   qt   = (bf16*)(ws + (34u << 20));          // [B][HW][C] bf16 : 16 MB
    bf16*   kT   = (bf16*)(ws + (50u << 20));          // [B][K][C] bf16  : 1 MB
    bf16*   vT   = (bf16*)(ws + (51u << 20));          // [B][K][C] bf16  : 1 MB
    char*   wbase = ws + (52u << 20);
    __bf16* Wq1p = (__bf16*)(wbase);
    __bf16* Wq2p = (__bf16*)(wbase + (32u << 10));
    __bf16* Wop  = (__bf16*)(wbase + (64u << 10));
    __bf16* Wbp  = (__bf16*)(wbase + (96u << 10));     // 128 KB
    __bf16* Wk1p = (__bf16*)(wbase + (224u << 10));
    __bf16* Wk2p = (__bf16*)(wbase + (256u << 10));
    __bf16* Wvp  = (__bf16*)(wbase + (288u << 10));
    float* outp = (float*)d_out;

    wprep_kernel<<<640, 256, 0, stream>>>(
        Wq1, sq1, Wq2, sq2, Wo, so, Wb, sb, Wk1, sk1, Wk2, sk2, Wv, sv,
        Wq1p, Wq2p, Wop, Wbp, Wk1p, Wk2p, Wvp);
    txp_kernel<<<dim3(288, B_), 256, 0, stream>>>(query, key, val, qt, kT, vT);
    proj_kernel<<<dim3(136, B_), 256, 0, stream>>>(
        qt, kT, vT, Wq1p, bq1, Wq2p, bq2, Wk1p, bk1, Wk2p, bk2, Wvp, bv,
        qbuf, kbuf, vbuf);
    attn_kernel<<<dim3(HW_ / 64, B_), 256, 0, stream>>>(
        qbuf, kbuf, vbuf, mask, ctxb);
    final_kernel<<<dim3(HW_ / 128, B_), 256, 0, stream>>>(
        ctxb, qt, Wop, bo, Wbp, bb, outp);
}

// Round 10
// 225.312 us; speedup vs baseline: 1.4394x; 1.0968x over previous
//
#include <hip/hip_runtime.h>
#include <hip/hip_bf16.h>

#define B_    4
#define C_    128
#define HW_   16384
#define K_    1024
#define NEG_  (-10000000.0f)
#define SCALE_ 0.08838834764831845f   // 128^-0.5

using bf16 = __hip_bfloat16;
typedef __bf16 b8v __attribute__((ext_vector_type(8)));
typedef __bf16 b4v __attribute__((ext_vector_type(4)));
typedef __bf16 b2v __attribute__((ext_vector_type(2)));
typedef float  f4v __attribute__((ext_vector_type(4)));

__device__ __forceinline__ b8v ldb8(const void* p) { return *(const b8v*)p; }
__device__ __forceinline__ b4v ldb4(const void* p) { return *(const b4v*)p; }

#define XSTRIDE 272   // 256 B row + 16 pad: b128 frag reads on the bank floor
#define KSTRIDE 272
#define VSTRIDE 136

// ---------------------------------------------------------------------------
// prep1: fused transpose (query/key/val [b][c][L] f32 -> [b][p][c] bf16) +
// weight fold/convert. grid 1792 x 256.
//   blk [0,1024)    : query transpose (b = blk>>8, seg = blk&255)
//   blk [1024,1152) : key/val transpose (32 segs per batch)
//   blk [1152,1792) : weight prep (163840 elems)
// ---------------------------------------------------------------------------
__global__ __launch_bounds__(256) void prep1_kernel(
    const float* __restrict__ query, const float* __restrict__ key, const float* __restrict__ val,
    const float* __restrict__ Wq1, const float* __restrict__ sq1,
    const float* __restrict__ Wq2, const float* __restrict__ sq2,
    const float* __restrict__ Wo,  const float* __restrict__ so,
    const float* __restrict__ Wb,  const float* __restrict__ sb,
    const float* __restrict__ Wk1, const float* __restrict__ sk1,
    const float* __restrict__ Wk2, const float* __restrict__ sk2,
    const float* __restrict__ Wv,  const float* __restrict__ sv,
    bf16* __restrict__ qt, bf16* __restrict__ kT, bf16* __restrict__ vT,
    __bf16* __restrict__ Wq1p, __bf16* __restrict__ Wq2p,
    __bf16* __restrict__ Wop,  __bf16* __restrict__ Wbp,
    __bf16* __restrict__ Wk1p, __bf16* __restrict__ Wk2p, __bf16* __restrict__ Wvp)
{
    __shared__ float Xs[64 * 129];
    const int blk = blockIdx.x, t = threadIdx.x;

    if (blk < 1152) {
        const float* src; bf16* dst; int L, p0, b;
        if (blk < 1024) {
            b = blk >> 8; src = query; dst = qt; L = HW_; p0 = (blk & 255) * 64;
        } else {
            const int i = blk - 1024;
            b = i >> 5; int j = i & 31;
            if (j < 16) { src = key; dst = kT; } else { src = val; dst = vT; j -= 16; }
            L = K_; p0 = j * 64;
        }
        const int pl = t & 63, cg = t >> 6;
#pragma unroll 4
        for (int i = 0; i < 32; ++i) {
            const int c = cg * 32 + i;
            Xs[pl * 129 + c] = src[(size_t)(b * 128 + c) * L + p0 + pl];
        }
        __syncthreads();
#pragma unroll 4
        for (int it = 0; it < 16; ++it) {
            const int p = it * 4 + cg;
            b2v pk;
            pk[0] = (__bf16)Xs[p * 129 + 2 * pl];
            pk[1] = (__bf16)Xs[p * 129 + 2 * pl + 1];
            *(b2v*)(dst + ((size_t)b * L + p0 + p) * 128 + 2 * pl) = pk;
        }
    } else {
        const int idx = (blk - 1152) * 256 + t;
        if (idx < 16384)       { Wq1p[idx] = (__bf16)(Wq1[idx] * sq1[idx >> 7]); }
        else if (idx < 32768)  { const int i = idx - 16384;  Wq2p[i] = (__bf16)(Wq2[i] * sq2[i >> 7]); }
        else if (idx < 49152)  { const int i = idx - 32768;  Wop[i]  = (__bf16)(Wo[i]  * so[i >> 7]); }
        else if (idx < 114688) { const int i = idx - 49152;  Wbp[i]  = (__bf16)(Wb[i]  * sb[i >> 8]); }
        else if (idx < 131072) { const int i = idx - 114688; Wk1p[i] = (__bf16)(Wk1[i] * sk1[i >> 7]); }
        else if (idx < 147456) { const int i = idx - 131072; Wk2p[i] = (__bf16)(Wk2[i] * sk2[i >> 7]); }
        else                   { const int i = idx - 147456; Wvp[i]  = (__bf16)(Wv[i]  * sv[i >> 7]); }
    }
}

// ---------------------------------------------------------------------------
// Generic MFMA 2-layer conv-bn-relu body on a 128-position tile (proven R9).
// ---------------------------------------------------------------------------
__device__ __forceinline__ void proj2_body(
    const bf16* __restrict__ src,
    const __bf16* __restrict__ W1, const float* __restrict__ sh1,
    const __bf16* __restrict__ W2, const float* __restrict__ sh2,
    bf16* __restrict__ dst, char* Xs, __bf16* Ys)
{
    const int t = threadIdx.x, w = t >> 6, lane = t & 63;
    const int pl = lane & 15, quad = lane >> 4;
    const int ob = 32 * w;

    {
        const char* sg = (const char*)src + t * 16;
        char* xl = Xs + (t >> 4) * XSTRIDE + (t & 15) * 16;
#pragma unroll
        for (int i = 0; i < 8; ++i)
            *(float4*)(xl + i * 16 * XSTRIDE) = *(const float4*)(sg + i * 4096);
    }

    b8v W1f[2][4], W2f[2][4];
#pragma unroll
    for (int mt = 0; mt < 2; ++mt)
#pragma unroll
        for (int s = 0; s < 4; ++s) {
            W1f[mt][s] = ldb8(W1 + (ob + mt * 16 + pl) * 128 + s * 32 + quad * 8);
            W2f[mt][s] = ldb8(W2 + (ob + mt * 16 + pl) * 128 + s * 32 + quad * 8);
        }
    __syncthreads();

    f4v acc[2][8];
#pragma unroll
    for (int mt = 0; mt < 2; ++mt)
#pragma unroll
        for (int nt = 0; nt < 8; ++nt) acc[mt][nt] = (f4v){0.f, 0.f, 0.f, 0.f};

#pragma unroll
    for (int s = 0; s < 4; ++s) {
        b8v Bf[8];
#pragma unroll
        for (int nt = 0; nt < 8; ++nt)
            Bf[nt] = ldb8(Xs + (nt * 16 + pl) * XSTRIDE + s * 64 + quad * 16);
#pragma unroll
        for (int mt = 0; mt < 2; ++mt)
#pragma unroll
            for (int nt = 0; nt < 8; ++nt)
                acc[mt][nt] = __builtin_amdgcn_mfma_f32_16x16x32_bf16(W1f[mt][s], Bf[nt], acc[mt][nt], 0, 0, 0);
    }

#pragma unroll
    for (int mt = 0; mt < 2; ++mt) {
        const float4 s4 = *(const float4*)(sh1 + ob + mt * 16 + quad * 4);
        const float shf[4] = {s4.x, s4.y, s4.z, s4.w};
#pragma unroll
        for (int nt = 0; nt < 8; ++nt) {
            b4v y;
#pragma unroll
            for (int r = 0; r < 4; ++r) y[r] = (__bf16)fmaxf(acc[mt][nt][r] + shf[r], 0.f);
            *(b4v*)&Ys[(nt * 16 + pl) * 136 + ob + mt * 16 + quad * 4] = y;
        }
    }
    __syncthreads();

    f4v acc2[2][8];
#pragma unroll
    for (int mt = 0; mt < 2; ++mt)
#pragma unroll
        for (int nt = 0; nt < 8; ++nt) acc2[mt][nt] = (f4v){0.f, 0.f, 0.f, 0.f};

#pragma unroll
    for (int s = 0; s < 4; ++s) {
        b8v Bf[8];
#pragma unroll
        for (int nt = 0; nt < 8; ++nt)
            Bf[nt] = *(const b8v*)&Ys[(nt * 16 + pl) * 136 + s * 32 + quad * 8];
#pragma unroll
        for (int mt = 0; mt < 2; ++mt)
#pragma unroll
            for (int nt = 0; nt < 8; ++nt)
                acc2[mt][nt] = __builtin_amdgcn_mfma_f32_16x16x32_bf16(W2f[mt][s], Bf[nt], acc2[mt][nt], 0, 0, 0);
    }

#pragma unroll
    for (int mt = 0; mt < 2; ++mt) {
        const float4 s4 = *(const float4*)(sh2 + ob + mt * 16 + quad * 4);
        const float shf[4] = {s4.x, s4.y, s4.z, s4.w};
#pragma unroll
        for (int nt = 0; nt < 8; ++nt) {
            b4v y;
#pragma unroll
            for (int r = 0; r < 4; ++r) y[r] = (__bf16)fmaxf(acc2[mt][nt][r] + shf[r], 0.f);
            *(b4v*)(dst + (size_t)(nt * 16 + pl) * 128 + ob + mt * 16 + quad * 4) = y;
        }
    }
}

// ---------------------------------------------------------------------------
// prep2: k projection (2 layers) -> kbuf [b][k][c]; v (1 layer) -> vbuf [b][c][k].
// grid (8, B), 256 threads. (R9 proven branch.)
// ---------------------------------------------------------------------------
__global__ __launch_bounds__(256, 2) void kvproj_kernel(
    const bf16* __restrict__ kT, const bf16* __restrict__ vT,
    const __bf16* __restrict__ Wk1p, const float* __restrict__ bk1,
    const __bf16* __restrict__ Wk2p, const float* __restrict__ bk2,
    const __bf16* __restrict__ Wvp,  const float* __restrict__ bv,
    bf16* __restrict__ kbuf, bf16* __restrict__ vbuf)
{
    __shared__ __align__(16) char Xs[128 * XSTRIDE];
    __shared__ __align__(16) __bf16 Ys[128 * 136];
    const int t = threadIdx.x, w = t >> 6, lane = t & 63;
    const int pl = lane & 15, quad = lane >> 4;
    const int b = blockIdx.y;
    const int n0 = blockIdx.x * 128;

    proj2_body(kT + ((size_t)b * K_ + n0) * 128, Wk1p, bk1, Wk2p, bk2,
               kbuf + ((size_t)b * K_ + n0) * 128, Xs, Ys);
    __syncthreads();

    {
        const char* sg = (const char*)(vT + ((size_t)b * K_ + n0) * 128) + t * 16;
        char* xl = Xs + (t >> 4) * XSTRIDE + (t & 15) * 16;
#pragma unroll
        for (int i = 0; i < 8; ++i)
            *(float4*)(xl + i * 16 * XSTRIDE) = *(const float4*)(sg + i * 4096);
    }
    const int ob = 32 * w;
    b8v Wf[2][4];
#pragma unroll
    for (int mt = 0; mt < 2; ++mt)
#pragma unroll
        for (int s = 0; s < 4; ++s)
            Wf[mt][s] = ldb8(Wvp + (ob + mt * 16 + pl) * 128 + s * 32 + quad * 8);
    __syncthreads();

    f4v acc[2][8];
#pragma unroll
    for (int mt = 0; mt < 2; ++mt)
#pragma unroll
        for (int nt = 0; nt < 8; ++nt) acc[mt][nt] = (f4v){0.f, 0.f, 0.f, 0.f};

#pragma unroll
    for (int s = 0; s < 4; ++s) {
        b8v Bf[8];
#pragma unroll
        for (int nt = 0; nt < 8; ++nt)
            Bf[nt] = ldb8(Xs + (nt * 16 + pl) * XSTRIDE + s * 64 + quad * 16);
#pragma unroll
        for (int mt = 0; mt < 2; ++mt)
#pragma unroll
            for (int nt = 0; nt < 8; ++nt)
                acc[mt][nt] = __builtin_amdgcn_mfma_f32_16x16x32_bf16(Wf[mt][s], Bf[nt], acc[mt][nt], 0, 0, 0);
    }

    bf16* vb = vbuf + (size_t)b * 128 * K_;
#pragma unroll
    for (int mt = 0; mt < 2; ++mt) {
        const float4 s4 = *(const float4*)(bv + ob + mt * 16 + quad * 4);
        const float shf[4] = {s4.x, s4.y, s4.z, s4.w};
#pragma unroll
        for (int nt = 0; nt < 8; ++nt)
#pragma unroll
            for (int r = 0; r < 4; ++r)
                vb[(size_t)(ob + mt * 16 + quad * 4 + r) * K_ + n0 + nt * 16 + pl]
                    = __float2bfloat16(fmaxf(acc[mt][nt][r] + shf[r], 0.f));
    }
}

// ---------------------------------------------------------------------------
// mega: qproj (phase 1) -> flash attention over 128 queries (phase 2) ->
// out-project + bottleneck (phase 3). One block = 128 queries, 256 threads.
// LDS: RA/RB (2 x 34816 B) re-purposed per phase. grid (HW/128, B).
// ---------------------------------------------------------------------------
__global__ __launch_bounds__(256, 2) void mega_kernel(
    const bf16* __restrict__ qt, const bf16* __restrict__ kbuf, const bf16* __restrict__ vbuf,
    const int* __restrict__ mask,
    const __bf16* __restrict__ Wq1p, const float* __restrict__ bq1,
    const __bf16* __restrict__ Wq2p, const float* __restrict__ bq2,
    const __bf16* __restrict__ Wop,  const float* __restrict__ bo,
    const __bf16* __restrict__ Wbp,  const float* __restrict__ bb,
    float* __restrict__ out)
{
    __shared__ __align__(16) char RA[128 * XSTRIDE];
    __shared__ __align__(16) char RB[128 * XSTRIDE];

    const int t = threadIdx.x, w = t >> 6, lane = t & 63;
    const int pl = lane & 15, quad = lane >> 4;
    const int n0 = blockIdx.x * 128;
    const int b  = blockIdx.y;
    const int ob = 32 * w;

    __bf16* RAh = (__bf16*)RA;
    __bf16* RBh = (__bf16*)RB;
    char* xl = RA + (t >> 4) * XSTRIDE + (t & 15) * 16;

    // ================= phase 1: q projection (into LDS) =================
    {
        const char* qg = (const char*)(qt + ((size_t)b * HW_ + n0) * 128) + t * 16;
#pragma unroll
        for (int i = 0; i < 8; ++i)
            *(float4*)(xl + i * 16 * XSTRIDE) = *(const float4*)(qg + i * 4096);
    }
    {
        b8v W1f[2][4], W2f[2][4];
#pragma unroll
        for (int mt = 0; mt < 2; ++mt)
#pragma unroll
            for (int s = 0; s < 4; ++s) {
                W1f[mt][s] = ldb8(Wq1p + (ob + mt * 16 + pl) * 128 + s * 32 + quad * 8);
                W2f[mt][s] = ldb8(Wq2p + (ob + mt * 16 + pl) * 128 + s * 32 + quad * 8);
            }
        __syncthreads();                       // sync1: q-tile in RA

        f4v a1[2][8];
#pragma unroll
        for (int mt = 0; mt < 2; ++mt)
#pragma unroll
            for (int nt = 0; nt < 8; ++nt) a1[mt][nt] = (f4v){0.f, 0.f, 0.f, 0.f};
#pragma unroll
        for (int s = 0; s < 4; ++s) {
            b8v Bf[8];
#pragma unroll
            for (int nt = 0; nt < 8; ++nt)
                Bf[nt] = ldb8(RA + (nt * 16 + pl) * XSTRIDE + s * 64 + quad * 16);
#pragma unroll
            for (int mt = 0; mt < 2; ++mt)
#pragma unroll
                for (int nt = 0; nt < 8; ++nt)
                    a1[mt][nt] = __builtin_amdgcn_mfma_f32_16x16x32_bf16(W1f[mt][s], Bf[nt], a1[mt][nt], 0, 0, 0);
        }
#pragma unroll
        for (int mt = 0; mt < 2; ++mt) {
            const float4 s4 = *(const float4*)(bq1 + ob + mt * 16 + quad * 4);
            const float shf[4] = {s4.x, s4.y, s4.z, s4.w};
#pragma unroll
            for (int nt = 0; nt < 8; ++nt) {
                b4v y;
#pragma unroll
                for (int r = 0; r < 4; ++r) y[r] = (__bf16)fmaxf(a1[mt][nt][r] + shf[r], 0.f);
                *(b4v*)&RBh[(nt * 16 + pl) * 136 + ob + mt * 16 + quad * 4] = y;
            }
        }
        __syncthreads();                       // sync2: y1 in RB, RA reads done

        f4v a2[2][8];
#pragma unroll
        for (int mt = 0; mt < 2; ++mt)
#pragma unroll
            for (int nt = 0; nt < 8; ++nt) a2[mt][nt] = (f4v){0.f, 0.f, 0.f, 0.f};
#pragma unroll
        for (int s = 0; s < 4; ++s) {
            b8v Bf[8];
#pragma unroll
            for (int nt = 0; nt < 8; ++nt)
                Bf[nt] = *(const b8v*)&RBh[(nt * 16 + pl) * 136 + s * 32 + quad * 8];
#pragma unroll
            for (int mt = 0; mt < 2; ++mt)
#pragma unroll
                for (int nt = 0; nt < 8; ++nt)
                    a2[mt][nt] = __builtin_amdgcn_mfma_f32_16x16x32_bf16(W2f[mt][s], Bf[nt], a2[mt][nt], 0, 0, 0);
        }
#pragma unroll
        for (int mt = 0; mt < 2; ++mt) {
            const float4 s4 = *(const float4*)(bq2 + ob + mt * 16 + quad * 4);
            const float shf[4] = {s4.x, s4.y, s4.z, s4.w};
#pragma unroll
            for (int nt = 0; nt < 8; ++nt) {
                b4v y;
#pragma unroll
                for (int r = 0; r < 4; ++r) y[r] = (__bf16)fmaxf(a2[mt][nt][r] + shf[r], 0.f);
                *(b4v*)&RAh[(nt * 16 + pl) * 136 + ob + mt * 16 + quad * 4] = y;
            }
        }
        __syncthreads();                       // sync3: q[pos][c] in RA
    }

    // q fragments: wave w owns queries w*32..w*32+31 (2 tiles)
    b8v qf0[4], qf1[4];
#pragma unroll
    for (int s = 0; s < 4; ++s) {
        qf0[s] = ldb8(RA + (w * 32 + pl) * XSTRIDE + s * 64 + quad * 16);
        qf1[s] = ldb8(RA + (w * 32 + 16 + pl) * XSTRIDE + s * 64 + quad * 16);
    }
    __syncthreads();                           // sync4: qf read, RA free

    // ================= phase 2: attention =================
    float* bias = (float*)RA;                  // 4096 B
    char* ktile = RA + 4096;                   // 64*272 = 17408 B
    char* vtile = RB;                          // 128*136 = 17408 B

    for (int i = t; i < K_; i += 256)
        bias[i] = (mask[b * K_ + i] != 0) ? 0.f : NEG_;

    const bf16* kpt = kbuf + (size_t)b * K_ * 128;
    const bf16* vpt = vbuf + (size_t)b * 128 * K_;
    const char* kg = (const char*)kpt + t * 16;
    const char* vg = (const char*)(vpt + (size_t)(t >> 3) * K_) + (t & 7) * 16;
    char* kl = ktile + (t >> 4) * KSTRIDE + (t & 15) * 16;
    char* vl = vtile + (t >> 3) * VSTRIDE + (t & 7) * 16;

    float4 k_r0 = *(const float4*)(kg);
    float4 k_r1 = *(const float4*)(kg + 4096);
    float4 k_r2 = *(const float4*)(kg + 8192);
    float4 k_r3 = *(const float4*)(kg + 12288);
    float4 v_r0 = *(const float4*)(vg);
    float4 v_r1 = *(const float4*)(vg + 65536);
    float4 v_r2 = *(const float4*)(vg + 131072);
    float4 v_r3 = *(const float4*)(vg + 196608);

    f4v ac0[8], ac1[8];
#pragma unroll
    for (int i = 0; i < 8; ++i) { ac0[i] = (f4v){0.f,0.f,0.f,0.f}; ac1[i] = (f4v){0.f,0.f,0.f,0.f}; }
    float mrun0 = -3.0e38f, mrun1 = -3.0e38f, lrun0 = 0.f, lrun1 = 0.f;

    for (int chunk = 0; chunk < 16; ++chunk) {
        const int k0 = chunk * 64;

        *(float4*)(kl)                = k_r0;
        *(float4*)(kl + 16 * KSTRIDE) = k_r1;
        *(float4*)(kl + 32 * KSTRIDE) = k_r2;
        *(float4*)(kl + 48 * KSTRIDE) = k_r3;
        *(float4*)(vl)                = v_r0;
        *(float4*)(vl + 32 * VSTRIDE) = v_r1;
        *(float4*)(vl + 64 * VSTRIDE) = v_r2;
        *(float4*)(vl + 96 * VSTRIDE) = v_r3;
        __syncthreads();

        if (chunk < 15) {
            const char* kgn = kg + (chunk + 1) * 16384;
            const char* vgn = vg + (chunk + 1) * 128;
            k_r0 = *(const float4*)(kgn);
            k_r1 = *(const float4*)(kgn + 4096);
            k_r2 = *(const float4*)(kgn + 8192);
            k_r3 = *(const float4*)(kgn + 12288);
            v_r0 = *(const float4*)(vgn);
            v_r1 = *(const float4*)(vgn + 65536);
            v_r2 = *(const float4*)(vgn + 131072);
            v_r3 = *(const float4*)(vgn + 196608);
        }

        // ---- GEMM1: k-frags loaded once, used for both q-tiles
        f4v sv0[4], sv1[4];
#pragma unroll
        for (int kt = 0; kt < 4; ++kt) {
            f4v a0 = (f4v){0.f,0.f,0.f,0.f}, a1 = (f4v){0.f,0.f,0.f,0.f};
            const char* krow = ktile + (kt * 16 + pl) * KSTRIDE + quad * 16;
#pragma unroll
            for (int s = 0; s < 4; ++s) {
                const b8v kf = ldb8(krow + s * 64);
                a0 = __builtin_amdgcn_mfma_f32_16x16x32_bf16(kf, qf0[s], a0, 0, 0, 0);
                a1 = __builtin_amdgcn_mfma_f32_16x16x32_bf16(kf, qf1[s], a1, 0, 0, 0);
            }
            const float4 b4 = *(const float4*)&bias[k0 + kt * 16 + quad * 4];
            const float bb4[4] = {b4.x, b4.y, b4.z, b4.w};
#pragma unroll
            for (int r = 0; r < 4; ++r) { sv0[kt][r] = a0[r] * SCALE_ + bb4[r];
                                          sv1[kt][r] = a1[r] * SCALE_ + bb4[r]; }
        }

        // ---- online softmax (2 q-tiles)
        float ml0 = sv0[0][0], ml1 = sv1[0][0];
#pragma unroll
        for (int kt = 0; kt < 4; ++kt)
#pragma unroll
            for (int r = 0; r < 4; ++r) { ml0 = fmaxf(ml0, sv0[kt][r]); ml1 = fmaxf(ml1, sv1[kt][r]); }
        ml0 = fmaxf(ml0, __shfl_xor(ml0, 16, 64)); ml0 = fmaxf(ml0, __shfl_xor(ml0, 32, 64));
        ml1 = fmaxf(ml1, __shfl_xor(ml1, 16, 64)); ml1 = fmaxf(ml1, __shfl_xor(ml1, 32, 64));
        const float mn0 = fmaxf(mrun0, ml0), mn1 = fmaxf(mrun1, ml1);
        const float al0 = __expf(mrun0 - mn0), al1 = __expf(mrun1 - mn1);
        mrun0 = mn0; mrun1 = mn1;

        b4v pk0[4], pk1[4];
        float rs0 = 0.f, rs1 = 0.f;
#pragma unroll
        for (int kt = 0; kt < 4; ++kt)
#pragma unroll
            for (int r = 0; r < 4; ++r) {
                const float p0 = __expf(sv0[kt][r] - mn0); rs0 += p0; pk0[kt][r] = (__bf16)p0;
                const float p1 = __expf(sv1[kt][r] - mn1); rs1 += p1; pk1[kt][r] = (__bf16)p1;
            }
        rs0 += __shfl_xor(rs0, 16, 64); rs0 += __shfl_xor(rs0, 32, 64);
        rs1 += __shfl_xor(rs1, 16, 64); rs1 += __shfl_xor(rs1, 32, 64);
        lrun0 = lrun0 * al0 + rs0;
        lrun1 = lrun1 * al1 + rs1;

        float ar0[4], ar1[4];
#pragma unroll
        for (int r = 0; r < 4; ++r) { ar0[r] = __shfl(al0, quad * 4 + r, 64);
                                      ar1[r] = __shfl(al1, quad * 4 + r, 64); }
#pragma unroll
        for (int ct = 0; ct < 8; ++ct)
#pragma unroll
            for (int r = 0; r < 4; ++r) { ac0[ct][r] *= ar0[r]; ac1[ct][r] *= ar1[r]; }

        // ---- GEMM2: v-frags loaded once, used for both q-tiles
        const b8v A00 = __builtin_shufflevector(pk0[0], pk0[1], 0, 1, 2, 3, 4, 5, 6, 7);
        const b8v A01 = __builtin_shufflevector(pk0[2], pk0[3], 0, 1, 2, 3, 4, 5, 6, 7);
        const b8v A10 = __builtin_shufflevector(pk1[0], pk1[1], 0, 1, 2, 3, 4, 5, 6, 7);
        const b8v A11 = __builtin_shufflevector(pk1[2], pk1[3], 0, 1, 2, 3, 4, 5, 6, 7);
#pragma unroll
        for (int ct = 0; ct < 8; ++ct) {
            const char* vrow = vtile + (ct * 16 + pl) * VSTRIDE + quad * 8;
            const b8v B0 = __builtin_shufflevector(ldb4(vrow),      ldb4(vrow + 32), 0, 1, 2, 3, 4, 5, 6, 7);
            const b8v B1 = __builtin_shufflevector(ldb4(vrow + 64), ldb4(vrow + 96), 0, 1, 2, 3, 4, 5, 6, 7);
            ac0[ct] = __builtin_amdgcn_mfma_f32_16x16x32_bf16(A00, B0, ac0[ct], 0, 0, 0);
            ac0[ct] = __builtin_amdgcn_mfma_f32_16x16x32_bf16(A01, B1, ac0[ct], 0, 0, 0);
            ac1[ct] = __builtin_amdgcn_mfma_f32_16x16x32_bf16(A10, B0, ac1[ct], 0, 0, 0);
            ac1[ct] = __builtin_amdgcn_mfma_f32_16x16x32_bf16(A11, B1, ac1[ct], 0, 0, 0);
        }
        __syncthreads();
    }

    // ---- epilogue: normalized ctx -> RA [pos][c] bf16
    {
        float inv0[4], inv1[4];
#pragma unroll
        for (int r = 0; r < 4; ++r) { inv0[r] = 1.f / __shfl(lrun0, quad * 4 + r, 64);
                                      inv1[r] = 1.f / __shfl(lrun1, quad * 4 + r, 64); }
#pragma unroll
        for (int ct = 0; ct < 8; ++ct)
#pragma unroll
            for (int r = 0; r < 4; ++r) {
                RAh[(w * 32 + quad * 4 + r) * 136 + ct * 16 + pl]      = (__bf16)(ac0[ct][r] * inv0[r]);
                RAh[(w * 32 + 16 + quad * 4 + r) * 136 + ct * 16 + pl] = (__bf16)(ac1[ct][r] * inv1[r]);
            }
    }
    __syncthreads();                           // sync5: ctx in RA

    // ================= phase 3: final =================
    b8v Wof[2][4];
#pragma unroll
    for (int mt = 0; mt < 2; ++mt)
#pragma unroll
        for (int s = 0; s < 4; ++s)
            Wof[mt][s] = ldb8(Wop + (ob + mt * 16 + pl) * 128 + s * 32 + quad * 8);

    const char* qg2 = (const char*)(qt + ((size_t)b * HW_ + n0) * 128) + t * 16;
    float4 q_s0 = *(const float4*)(qg2);
    float4 q_s1 = *(const float4*)(qg2 + 4096);
    float4 q_s2 = *(const float4*)(qg2 + 8192);
    float4 q_s3 = *(const float4*)(qg2 + 12288);
    float4 q_s4 = *(const float4*)(qg2 + 16384);
    float4 q_s5 = *(const float4*)(qg2 + 20480);
    float4 q_s6 = *(const float4*)(qg2 + 24576);
    float4 q_s7 = *(const float4*)(qg2 + 28672);

    {
        f4v f1[2][8];
#pragma unroll
        for (int mt = 0; mt < 2; ++mt)
#pragma unroll
            for (int nt = 0; nt < 8; ++nt) f1[mt][nt] = (f4v){0.f, 0.f, 0.f, 0.f};
#pragma unroll
        for (int s = 0; s < 4; ++s) {
            b8v Bf[8];
#pragma unroll
            for (int nt = 0; nt < 8; ++nt)
                Bf[nt] = ldb8(RA + (nt * 16 + pl) * XSTRIDE + s * 64 + quad * 16);
#pragma unroll
            for (int mt = 0; mt < 2; ++mt)
#pragma unroll
                for (int nt = 0; nt < 8; ++nt)
                    f1[mt][nt] = __builtin_amdgcn_mfma_f32_16x16x32_bf16(Wof[mt][s], Bf[nt], f1[mt][nt], 0, 0, 0);
        }
#pragma unroll
        for (int mt = 0; mt < 2; ++mt) {
            const float4 s4 = *(const float4*)(bo + ob + mt * 16 + quad * 4);
            const float shf[4] = {s4.x, s4.y, s4.z, s4.w};
#pragma unroll
            for (int nt = 0; nt < 8; ++nt) {
                b4v y;
#pragma unroll
                for (int r = 0; r < 4; ++r) y[r] = (__bf16)fmaxf(f1[mt][nt][r] + shf[r], 0.f);
                *(b4v*)&RBh[(nt * 16 + pl) * 136 + ob + mt * 16 + quad * 4] = y;
            }
        }
    }
    __syncthreads();                           // sync6: ctx2 in RB, RA reads done

    *(float4*)(xl)                 = q_s0;
    *(float4*)(xl + 16 * XSTRIDE)  = q_s1;
    *(float4*)(xl + 32 * XSTRIDE)  = q_s2;
    *(float4*)(xl + 48 * XSTRIDE)  = q_s3;
    *(float4*)(xl + 64 * XSTRIDE)  = q_s4;
    *(float4*)(xl + 80 * XSTRIDE)  = q_s5;
    *(float4*)(xl + 96 * XSTRIDE)  = q_s6;
    *(float4*)(xl + 112 * XSTRIDE) = q_s7;
    __syncthreads();                           // sync7: qt in RA

    {
        f4v f2[4][8];
#pragma unroll
        for (int mt = 0; mt < 4; ++mt)
#pragma unroll
            for (int nt = 0; nt < 8; ++nt) f2[mt][nt] = (f4v){0.f, 0.f, 0.f, 0.f};
#pragma unroll
        for (int ks = 0; ks < 8; ++ks) {
            b8v Af[4];
#pragma unroll
            for (int mt = 0; mt < 4; ++mt)
                Af[mt] = ldb8(Wbp + (size_t)(64 * w + mt * 16 + pl) * 256 + ks * 32 + quad * 8);
            b8v Bf[8];
            if (ks < 4) {
#pragma unroll
                for (int nt = 0; nt < 8; ++nt)
                    Bf[nt] = *(const b8v*)&RBh[(nt * 16 + pl) * 136 + ks * 32 + quad * 8];
            } else {
#pragma unroll
                for (int nt = 0; nt < 8; ++nt)
                    Bf[nt] = ldb8(RA + (nt * 16 + pl) * XSTRIDE + (ks - 4) * 64 + quad * 16);
            }
#pragma unroll
            for (int mt = 0; mt < 4; ++mt)
#pragma unroll
                for (int nt = 0; nt < 8; ++nt)
                    f2[mt][nt] = __builtin_amdgcn_mfma_f32_16x16x32_bf16(Af[mt], Bf[nt], f2[mt][nt], 0, 0, 0);
        }
#pragma unroll
        for (int mt = 0; mt < 4; ++mt) {
            const float4 s4 = *(const float4*)(bb + 64 * w + mt * 16 + quad * 4);
            const float shf[4] = {s4.x, s4.y, s4.z, s4.w};
#pragma unroll
            for (int nt = 0; nt < 8; ++nt)
#pragma unroll
                for (int r = 0; r < 4; ++r)
                    out[(size_t)(b * 256 + 64 * w + mt * 16 + quad * 4 + r) * HW_ + n0 + nt * 16 + pl]
                        = fmaxf(f2[mt][nt][r] + shf[r], 0.f);
        }
    }
}

// ---------------------------------------------------------------------------
extern "C" void kernel_launch(void* const* d_in, const int* in_sizes, int n_in,
                              void* d_out, int out_size, void* d_ws, size_t ws_size,
                              hipStream_t stream)
{
    const float* query = (const float*)d_in[0];
    const float* key   = (const float*)d_in[1];
    const float* val   = (const float*)d_in[2];
    const int*   mask  = (const int*)  d_in[3];
    const float* Wq1 = (const float*)d_in[4];  const float* sq1 = (const float*)d_in[5];  const float* bq1 = (const float*)d_in[6];
    const float* Wq2 = (const float*)d_in[7];  const float* sq2 = (const float*)d_in[8];  const float* bq2 = (const float*)d_in[9];
    const float* Wk1 = (const float*)d_in[10]; const float* sk1 = (const float*)d_in[11]; const float* bk1 = (const float*)d_in[12];
    const float* Wk2 = (const float*)d_in[13]; const float* sk2 = (const float*)d_in[14]; const float* bk2 = (const float*)d_in[15];
    const float* Wv  = (const float*)d_in[16]; const float* sv  = (const float*)d_in[17]; const float* bv  = (const float*)d_in[18];
    const float* Wo  = (const float*)d_in[19]; const float* so  = (const float*)d_in[20]; const float* bo  = (const float*)d_in[21];
    const float* Wb  = (const float*)d_in[22]; const float* sb  = (const float*)d_in[23]; const float* bb  = (const float*)d_in[24];

    char* ws = (char*)d_ws;
    bf16*   qt   = (bf16*)(ws);                        // [B][HW][C] bf16 : 16 MB
    bf16*   kT   = (bf16*)(ws + (16u << 20));          // [B][K][C]  bf16 : 1 MB
    bf16*   vT   = (bf16*)(ws + (17u << 20));          // [B][K][C]  bf16 : 1 MB
    bf16*   kbuf = (bf16*)(ws + (18u << 20));          // [B][K][C]  bf16 : 1 MB
    bf16*   vbuf = (bf16*)(ws + (19u << 20));          // [B][C][K]  bf16 : 1 MB
    char*   wbase = ws + (20u << 20);
    __bf16* Wq1p = (__bf16*)(wbase);
    __bf16* Wq2p = (__bf16*)(wbase + (32u << 10));
    __bf16* Wop  = (__bf16*)(wbase + (64u << 10));
    __bf16* Wbp  = (__bf16*)(wbase + (96u << 10));     // 128 KB
    __bf16* Wk1p = (__bf16*)(wbase + (224u << 10));
    __bf16* Wk2p = (__bf16*)(wbase + (256u << 10));
    __bf16* Wvp  = (__bf16*)(wbase + (288u << 10));
    float* outp = (float*)d_out;

    prep1_kernel<<<1792, 256, 0, stream>>>(
        query, key, val,
        Wq1, sq1, Wq2, sq2, Wo, so, Wb, sb, Wk1, sk1, Wk2, sk2, Wv, sv,
        qt, kT, vT, Wq1p, Wq2p, Wop, Wbp, Wk1p, Wk2p, Wvp);
    kvproj_kernel<<<dim3(8, B_), 256, 0, stream>>>(
        kT, vT, Wk1p, bk1, Wk2p, bk2, Wvp, bv, kbuf, vbuf);
    mega_kernel<<<dim3(HW_ / 128, B_), 256, 0, stream>>>(
        qt, kbuf, vbuf, mask,
        Wq1p, bq1, Wq2p, bq2, Wop, bo, Wbp, bb, outp);
}